// Round 1
// baseline (560.421 us; speedup 1.0000x reference)
//
#include <hip/hip_runtime.h>
#include <math.h>

#define DH 128

// ---------------- CSR build ----------------

__global__ void count_kernel(const int* __restrict__ col, int* __restrict__ cnt, int e) {
  int i = blockIdx.x * blockDim.x + threadIdx.x;
  if (i < e) atomicAdd(&cnt[col[i]], 1);
}

// single-block exclusive scan of cnt -> rowptr, plus dinv = rsqrt(cnt+1)
__global__ __launch_bounds__(1024) void scan_kernel(const int* __restrict__ cnt,
                                                    int* __restrict__ rowptr,
                                                    float* __restrict__ dinv, int n) {
  __shared__ int wsum[16];
  __shared__ int carry;
  if (threadIdx.x == 0) carry = 0;
  __syncthreads();
  const int lane = threadIdx.x & 63;
  const int wid = threadIdx.x >> 6;
  for (int base = 0; base < n; base += 1024) {
    int i = base + threadIdx.x;
    int v = (i < n) ? cnt[i] : 0;
    int s = v;
#pragma unroll
    for (int d = 1; d < 64; d <<= 1) {
      int t = __shfl_up(s, d);
      if (lane >= d) s += t;
    }
    if (lane == 63) wsum[wid] = s;
    __syncthreads();
    if (wid == 0 && lane < 16) {
      int ws = wsum[lane];
#pragma unroll
      for (int d = 1; d < 16; d <<= 1) {
        int t = __shfl_up(ws, d);
        if (lane >= d) ws += t;
      }
      wsum[lane] = ws;  // inclusive scan of wave sums
    }
    __syncthreads();
    int offset = carry + (wid > 0 ? wsum[wid - 1] : 0);
    if (i < n) {
      rowptr[i] = offset + s - v;  // exclusive
      dinv[i] = rsqrtf((float)(v + 1));
    }
    __syncthreads();
    if (threadIdx.x == 0) carry += wsum[15];
    __syncthreads();
  }
  if (threadIdx.x == 0) rowptr[n] = carry;
}

__global__ void fill_kernel(const int* __restrict__ row, const int* __restrict__ col,
                            const int* __restrict__ rowptr, int* __restrict__ cursor,
                            int* __restrict__ csr_src, int e) {
  int i = blockIdx.x * blockDim.x + threadIdx.x;
  if (i < e) {
    int c = col[i];
    int pos = rowptr[c] + atomicAdd(&cursor[c], 1);
    csr_src[pos] = row[i];
  }
}

// ---------------- GEMM: C[n,128] = A[n,K] @ W[K,128] (+bias, relu) ----------------

template <int K, bool BIAS_RELU>
__global__ __launch_bounds__(256) void matmul_kernel(const float* __restrict__ A,
                                                     const float* __restrict__ W,
                                                     const float* __restrict__ bias,
                                                     float* __restrict__ C, int n) {
  __shared__ float xs[32][64];
  __shared__ float ws[64][DH];
  const int t = threadIdx.x;
  const int c4 = (t & 31) * 4;   // 4 output cols
  const int r4 = (t >> 5) * 4;   // 4 output rows within the 32-row tile
  const int r0 = blockIdx.x * 32;
  float acc[4][4] = {};
  for (int kb = 0; kb < K; kb += 64) {
    // stage A tile: 32 rows x 64 k (float4)
#pragma unroll
    for (int i = 0; i < 2; i++) {
      int id = t + i * 256;
      int r = id >> 4, kk = (id & 15) * 4;
      int gr = r0 + r;
      float4 v;
      if (gr < n) v = *(const float4*)&A[(size_t)gr * K + kb + kk];
      else        v = make_float4(0.f, 0.f, 0.f, 0.f);
      *(float4*)&xs[r][kk] = v;
    }
    // stage W tile: 64 k x 128 cols (float4)
#pragma unroll
    for (int i = 0; i < 8; i++) {
      int id = t + i * 256;
      int k = id >> 5, cc = (id & 31) * 4;
      *(float4*)&ws[k][cc] = *(const float4*)&W[(size_t)(kb + k) * DH + cc];
    }
    __syncthreads();
#pragma unroll
    for (int k = 0; k < 64; k++) {
      float4 wv = *(const float4*)&ws[k][c4];
#pragma unroll
      for (int r = 0; r < 4; r++) {
        float av = xs[r4 + r][k];
        acc[r][0] = fmaf(av, wv.x, acc[r][0]);
        acc[r][1] = fmaf(av, wv.y, acc[r][1]);
        acc[r][2] = fmaf(av, wv.z, acc[r][2]);
        acc[r][3] = fmaf(av, wv.w, acc[r][3]);
      }
    }
    __syncthreads();
  }
  float4 bv = make_float4(0.f, 0.f, 0.f, 0.f);
  if (BIAS_RELU) bv = *(const float4*)&bias[c4];
#pragma unroll
  for (int r = 0; r < 4; r++) {
    int gr = r0 + r4 + r;
    if (gr < n) {
      float4 o;
      o.x = acc[r][0] + bv.x;
      o.y = acc[r][1] + bv.y;
      o.z = acc[r][2] + bv.z;
      o.w = acc[r][3] + bv.w;
      if (BIAS_RELU) {
        o.x = fmaxf(o.x, 0.f); o.y = fmaxf(o.y, 0.f);
        o.z = fmaxf(o.z, 0.f); o.w = fmaxf(o.w, 0.f);
      }
      *(float4*)&C[(size_t)gr * DH + c4] = o;
    }
  }
}

// ---------------- aggregation: h = relu(h + D^-1/2 (A+I) D^-1/2 (h W) + b) ----------------

__global__ __launch_bounds__(128) void agg_kernel(const float* __restrict__ xw,
                                                  const float* __restrict__ dinv,
                                                  const int* __restrict__ rowptr,
                                                  const int* __restrict__ csr_src,
                                                  const float* __restrict__ bias,
                                                  float* __restrict__ h, int n) {
  const int nd = blockIdx.x;
  const int c = threadIdx.x;
  const float self = dinv[nd];
  float acc = self * self * xw[(size_t)nd * DH + c];  // self loop: norm = dinv^2
  const int beg = rowptr[nd], end = rowptr[nd + 1];
  for (int j = beg; j < end; j++) {
    int s = csr_src[j];
    acc = fmaf(dinv[s] * self, xw[(size_t)s * DH + c], acc);
  }
  float v = h[(size_t)nd * DH + c] + acc + bias[c];
  h[(size_t)nd * DH + c] = fmaxf(v, 0.f);
}

// ---------------- MLP head: out = sigmoid(hidden @ w2 + b2) ----------------

__global__ __launch_bounds__(256) void mlp_out_kernel(const float* __restrict__ hid,
                                                      const float* __restrict__ w2,
                                                      const float* __restrict__ b2,
                                                      float* __restrict__ out, int n) {
  const int wid = (int)((blockIdx.x * (size_t)blockDim.x + threadIdx.x) >> 6);
  const int lane = threadIdx.x & 63;
  if (wid >= n) return;
  float s = hid[(size_t)wid * DH + lane] * w2[lane] +
            hid[(size_t)wid * DH + 64 + lane] * w2[64 + lane];
#pragma unroll
  for (int d = 32; d; d >>= 1) s += __shfl_down(s, d);
  if (lane == 0) out[wid] = 1.f / (1.f + __expf(-(s + b2[0])));
}

// ---------------- launch ----------------

extern "C" void kernel_launch(void* const* d_in, const int* in_sizes, int n_in,
                              void* d_out, int out_size, void* d_ws, size_t ws_size,
                              hipStream_t stream) {
  const float* x     = (const float*)d_in[0];
  const int*   ei    = (const int*)d_in[1];
  const float* w_in  = (const float*)d_in[2];
  const float* b_in  = (const float*)d_in[3];
  const float* w_gcn = (const float*)d_in[4];
  const float* b_gcn = (const float*)d_in[5];
  const float* w_nc1 = (const float*)d_in[6];
  const float* b_nc1 = (const float*)d_in[7];
  const float* w_nc2 = (const float*)d_in[8];
  const float* b_nc2 = (const float*)d_in[9];
  const float* w_oc1 = (const float*)d_in[10];
  const float* b_oc1 = (const float*)d_in[11];
  const float* w_oc2 = (const float*)d_in[12];
  const float* b_oc2 = (const float*)d_in[13];

  const int N = in_sizes[0] / 256;  // 50000
  const int E = in_sizes[1] / 2;    // 600000
  const int* erow = ei;
  const int* ecol = ei + E;

  float* out      = (float*)d_out;
  float* out_node = out;
  float* out_orig = out + N;
  float* out_err  = out + 2 * (size_t)N;
  float* h        = out + 6 * (size_t)N;  // final h lives directly in d_out

  // workspace carve (≈28.8 MB)
  float* xw   = (float*)d_ws;                 // N*128 f32
  float* dinv = xw + (size_t)N * DH;          // N f32
  int* cnt    = (int*)(dinv + N);             // N
  int* rowptr = cnt + N;                      // N+1
  int* cursor = rowptr + N + 1;               // N
  int* csr    = cursor + N;                   // E

  hipMemsetAsync(cnt, 0, N * sizeof(int), stream);
  hipMemsetAsync(cursor, 0, N * sizeof(int), stream);
  hipMemsetAsync(out_err, 0, 4 * (size_t)N * sizeof(float), stream);

  const int eb = (E + 255) / 256;
  count_kernel<<<eb, 256, 0, stream>>>(ecol, cnt, E);
  scan_kernel<<<1, 1024, 0, stream>>>(cnt, rowptr, dinv, N);
  fill_kernel<<<eb, 256, 0, stream>>>(erow, ecol, rowptr, cursor, csr, E);

  const int mb = (N + 31) / 32;
  // h = relu(x @ w_in + b_in)
  matmul_kernel<256, true><<<mb, 256, 0, stream>>>(x, w_in, b_in, h, N);
  // 3 GCN layers
  for (int l = 0; l < 3; l++) {
    matmul_kernel<128, false><<<mb, 256, 0, stream>>>(h, w_gcn + (size_t)l * DH * DH,
                                                      nullptr, xw, N);
    agg_kernel<<<N, 128, 0, stream>>>(xw, dinv, rowptr, csr, b_gcn + (size_t)l * DH, h, N);
  }
  // heads
  matmul_kernel<128, true><<<mb, 256, 0, stream>>>(h, w_nc1, b_nc1, xw, N);
  mlp_out_kernel<<<(N + 3) / 4, 256, 0, stream>>>(xw, w_nc2, b_nc2, out_node, N);
  matmul_kernel<128, true><<<mb, 256, 0, stream>>>(h, w_oc1, b_oc1, xw, N);
  mlp_out_kernel<<<(N + 3) / 4, 256, 0, stream>>>(xw, w_oc2, b_oc2, out_orig, N);
}

// Round 2
// 323.184 us; speedup vs baseline: 1.7341x; 1.7341x over previous
//
#include <hip/hip_runtime.h>
#include <math.h>

#define DH 128

typedef short short8 __attribute__((ext_vector_type(8)));
typedef float f32x4 __attribute__((ext_vector_type(4)));

__device__ __forceinline__ unsigned short f2bu(float f) {
  unsigned int u = __builtin_bit_cast(unsigned int, f);
  unsigned int r = (u + 0x7fffu + ((u >> 16) & 1u)) >> 16;
  return (unsigned short)r;
}
__device__ __forceinline__ float blo(unsigned int u) {
  return __builtin_bit_cast(float, u << 16);
}
__device__ __forceinline__ float bhi(unsigned int u) {
  return __builtin_bit_cast(float, u & 0xffff0000u);
}
__device__ __forceinline__ unsigned int packb2(float a, float b) {
  return (unsigned int)f2bu(a) | ((unsigned int)f2bu(b) << 16);
}

// ---------------- weight transpose fp32 [K][128] -> bf16 [128][K] ----------------

__global__ void wtrans_kernel(const float* __restrict__ W, unsigned short* __restrict__ WT,
                              int K) {
  int idx = blockIdx.x * 256 + threadIdx.x;
  if (idx < K * DH) {
    int k = idx >> 7, c = idx & 127;
    WT[c * K + k] = f2bu(W[idx]);
  }
}

// ---------------- x fp32 -> bf16 (row-major, same layout) ----------------

__global__ void xconv_kernel(const float* __restrict__ x, unsigned short* __restrict__ xb,
                             int total4) {
  int i = blockIdx.x * 256 + threadIdx.x;
  if (i < total4) {
    float4 v = *(const float4*)&x[(size_t)i * 4];
    unsigned short o[4] = {f2bu(v.x), f2bu(v.y), f2bu(v.z), f2bu(v.w)};
    *(uint2*)&xb[(size_t)i * 4] = *(const uint2*)o;
  }
}

// ---------------- CSR build ----------------

__global__ void count_kernel(const int* __restrict__ col, int* __restrict__ cnt, int e) {
  int i = blockIdx.x * blockDim.x + threadIdx.x;
  if (i < e) atomicAdd(&cnt[col[i]], 1);
}

__global__ __launch_bounds__(1024) void scan1_kernel(const int* __restrict__ cnt,
                                                     int* __restrict__ rowptr,
                                                     float* __restrict__ dinv,
                                                     int* __restrict__ bsum, int n) {
  __shared__ int wsum[16];
  const int t = threadIdx.x;
  const int lane = t & 63, wid = t >> 6;
  const int i = blockIdx.x * 1024 + t;
  int v = (i < n) ? cnt[i] : 0;
  int s = v;
#pragma unroll
  for (int d = 1; d < 64; d <<= 1) {
    int u = __shfl_up(s, d);
    if (lane >= d) s += u;
  }
  if (lane == 63) wsum[wid] = s;
  __syncthreads();
  if (t < 16) {
    int ws = wsum[t];
#pragma unroll
    for (int d = 1; d < 16; d <<= 1) {
      int u = __shfl_up(ws, d);
      if (t >= d) ws += u;
    }
    wsum[t] = ws;
  }
  __syncthreads();
  if (i < n) {
    rowptr[i] = (wid ? wsum[wid - 1] : 0) + s - v;
    dinv[i] = rsqrtf((float)(v + 1));
  }
  if (t == 0) bsum[blockIdx.x] = wsum[15];
}

__global__ void scan2_kernel(int* __restrict__ bsum, int nb, int* __restrict__ rowptr_n) {
  int lane = threadIdx.x;
  int v = (lane < nb) ? bsum[lane] : 0;
  int s = v;
#pragma unroll
  for (int d = 1; d < 64; d <<= 1) {
    int u = __shfl_up(s, d);
    if (lane >= d) s += u;
  }
  if (lane < nb) bsum[lane] = s - v;
  if (lane == 63) *rowptr_n = s;
}

__global__ void scan3_kernel(int* __restrict__ rowptr, const int* __restrict__ bsum, int n) {
  int i = blockIdx.x * 256 + threadIdx.x;
  if (i < n) rowptr[i] += bsum[i >> 10];
}

__global__ void fill_kernel(const int* __restrict__ row, const int* __restrict__ col,
                            const int* __restrict__ rowptr, int* __restrict__ cursor,
                            int* __restrict__ csr_src, int e) {
  int i = blockIdx.x * blockDim.x + threadIdx.x;
  if (i < e) {
    int c = col[i];
    int pos = rowptr[c] + atomicAdd(&cursor[c], 1);
    csr_src[pos] = row[i];
  }
}

// ---------------- bf16 MFMA GEMM: C[n,128] = A[n,K] @ W[K,128] ----------------
// WT is bf16 [128][K] (W transposed). MODE 0: store bf16 raw. MODE 1: bias+relu,
// store fp32 + bf16. MODE 2: bias+relu, store bf16 only.

template <int K, bool A_FP32, int MODE>
__global__ __launch_bounds__(256) void gemm_kernel(const void* __restrict__ A_,
                                                   const unsigned short* __restrict__ WT,
                                                   const float* __restrict__ bias,
                                                   float* __restrict__ Cf,
                                                   unsigned short* __restrict__ Cb, int n) {
  const int t = threadIdx.x;
  const int lane = t & 63;
  const int w = t >> 6;
  const int wr = w >> 1, wc = w & 1;
  const int lr = lane & 15, lg = lane >> 4;
  const int r_base = blockIdx.x * 128 + wr * 64;
  const int c_base = wc * 64;

  f32x4 acc[4][4] = {};

#pragma unroll
  for (int kk = 0; kk < K / 32; kk++) {
    const int koff = kk * 32 + lg * 8;
    short8 a[4], b[4];
#pragma unroll
    for (int m = 0; m < 4; m++) {
      int row = r_base + m * 16 + lr;
      row = row < n ? row : n - 1;
      if (A_FP32) {
        const float* Af = (const float*)A_;
        float4 p = *(const float4*)&Af[(size_t)row * K + koff];
        float4 q = *(const float4*)&Af[(size_t)row * K + koff + 4];
        short8 av;
        av[0] = (short)f2bu(p.x); av[1] = (short)f2bu(p.y);
        av[2] = (short)f2bu(p.z); av[3] = (short)f2bu(p.w);
        av[4] = (short)f2bu(q.x); av[5] = (short)f2bu(q.y);
        av[6] = (short)f2bu(q.z); av[7] = (short)f2bu(q.w);
        a[m] = av;
      } else {
        const unsigned short* Ab = (const unsigned short*)A_;
        a[m] = *(const short8*)&Ab[(size_t)row * K + koff];
      }
    }
#pragma unroll
    for (int nb = 0; nb < 4; nb++) {
      int col = c_base + nb * 16 + lr;
      b[nb] = *(const short8*)&WT[(size_t)col * K + koff];
    }
#pragma unroll
    for (int m = 0; m < 4; m++)
#pragma unroll
      for (int nb = 0; nb < 4; nb++)
        acc[m][nb] = __builtin_amdgcn_mfma_f32_16x16x32_bf16(a[m], b[nb], acc[m][nb], 0, 0, 0);
  }

  float bcol[4];
  if (MODE != 0) {
#pragma unroll
    for (int nb = 0; nb < 4; nb++) bcol[nb] = bias[c_base + nb * 16 + lr];
  }

#pragma unroll
  for (int m = 0; m < 4; m++) {
#pragma unroll
    for (int i = 0; i < 4; i++) {
      int row = r_base + m * 16 + lg * 4 + i;
      if (row < n) {
#pragma unroll
        for (int nb = 0; nb < 4; nb++) {
          int col = c_base + nb * 16 + lr;
          float v = acc[m][nb][i];
          if (MODE != 0) v = fmaxf(v + bcol[nb], 0.f);
          if (MODE == 1) Cf[(size_t)row * DH + col] = v;
          Cb[(size_t)row * DH + col] = f2bu(v);
        }
      }
    }
  }
}

// ---------------- aggregation: h = relu(h + D^-1/2 (A+I) D^-1/2 (h W) + b) ----------------
// xwb: bf16 xw as uint pairs [n][64]; updates h (fp32) and hb (bf16).

__global__ __launch_bounds__(256) void agg_kernel(const unsigned int* __restrict__ xwb,
                                                  const float* __restrict__ dinv,
                                                  const int* __restrict__ rowptr,
                                                  const int* __restrict__ csr_src,
                                                  const float* __restrict__ bias,
                                                  float* __restrict__ h,
                                                  unsigned int* __restrict__ hb, int n) {
  const int node = blockIdx.x * 4 + (threadIdx.x >> 6);
  if (node >= n) return;
  const int lane = threadIdx.x & 63;
  const float self = dinv[node];

  unsigned int us = xwb[(size_t)node * 64 + lane];
  float a0 = self * self * blo(us);
  float a1 = self * self * bhi(us);

  const int beg = rowptr[node], end = rowptr[node + 1];
  int j = beg;
  for (; j + 4 <= end; j += 4) {
    int s0 = csr_src[j], s1 = csr_src[j + 1], s2 = csr_src[j + 2], s3 = csr_src[j + 3];
    float w0 = dinv[s0] * self, w1 = dinv[s1] * self;
    float w2 = dinv[s2] * self, w3 = dinv[s3] * self;
    unsigned int u0 = xwb[(size_t)s0 * 64 + lane];
    unsigned int u1 = xwb[(size_t)s1 * 64 + lane];
    unsigned int u2 = xwb[(size_t)s2 * 64 + lane];
    unsigned int u3 = xwb[(size_t)s3 * 64 + lane];
    a0 = fmaf(w0, blo(u0), a0); a1 = fmaf(w0, bhi(u0), a1);
    a0 = fmaf(w1, blo(u1), a0); a1 = fmaf(w1, bhi(u1), a1);
    a0 = fmaf(w2, blo(u2), a0); a1 = fmaf(w2, bhi(u2), a1);
    a0 = fmaf(w3, blo(u3), a0); a1 = fmaf(w3, bhi(u3), a1);
  }
  for (; j < end; j++) {
    int s = csr_src[j];
    float ww = dinv[s] * self;
    unsigned int u = xwb[(size_t)s * 64 + lane];
    a0 = fmaf(ww, blo(u), a0);
    a1 = fmaf(ww, bhi(u), a1);
  }

  const float2 bv = *(const float2*)&bias[lane * 2];
  const float2 hv = *(const float2*)&h[(size_t)node * DH + lane * 2];
  float r0 = fmaxf(hv.x + a0 + bv.x, 0.f);
  float r1 = fmaxf(hv.y + a1 + bv.y, 0.f);
  *(float2*)&h[(size_t)node * DH + lane * 2] = make_float2(r0, r1);
  hb[(size_t)node * 64 + lane] = packb2(r0, r1);
}

// ---------------- MLP head: out = sigmoid(hidden_bf16 @ w2 + b2) ----------------

__global__ __launch_bounds__(256) void mlp_out_kernel(const unsigned int* __restrict__ hid,
                                                      const float* __restrict__ w2,
                                                      const float* __restrict__ b2,
                                                      float* __restrict__ out, int n) {
  const int wid = (int)((blockIdx.x * (size_t)blockDim.x + threadIdx.x) >> 6);
  const int lane = threadIdx.x & 63;
  if (wid >= n) return;
  unsigned int u = hid[(size_t)wid * 64 + lane];
  const float2 wv = *(const float2*)&w2[lane * 2];
  float s = blo(u) * wv.x + bhi(u) * wv.y;
#pragma unroll
  for (int d = 32; d; d >>= 1) s += __shfl_down(s, d);
  if (lane == 0) out[wid] = 1.f / (1.f + __expf(-(s + b2[0])));
}

// ---------------- launch ----------------

extern "C" void kernel_launch(void* const* d_in, const int* in_sizes, int n_in,
                              void* d_out, int out_size, void* d_ws, size_t ws_size,
                              hipStream_t stream) {
  const float* x     = (const float*)d_in[0];
  const int*   ei    = (const int*)d_in[1];
  const float* w_in  = (const float*)d_in[2];
  const float* b_in  = (const float*)d_in[3];
  const float* w_gcn = (const float*)d_in[4];
  const float* b_gcn = (const float*)d_in[5];
  const float* w_nc1 = (const float*)d_in[6];
  const float* b_nc1 = (const float*)d_in[7];
  const float* w_nc2 = (const float*)d_in[8];
  const float* b_nc2 = (const float*)d_in[9];
  const float* w_oc1 = (const float*)d_in[10];
  const float* b_oc1 = (const float*)d_in[11];
  const float* w_oc2 = (const float*)d_in[12];
  const float* b_oc2 = (const float*)d_in[13];

  const int N = in_sizes[0] / 256;  // 50000
  const int E = in_sizes[1] / 2;    // 600000
  const int* erow = ei;
  const int* ecol = ei + E;

  float* out      = (float*)d_out;
  float* out_node = out;
  float* out_orig = out + N;
  float* out_err  = out + 2 * (size_t)N;
  float* h        = out + 6 * (size_t)N;  // final h lives directly in d_out

  // workspace carve
  unsigned short* xwb = (unsigned short*)d_ws;           // N*128 bf16
  unsigned short* hb  = xwb + (size_t)N * DH;            // N*128 bf16
  unsigned short* wT  = hb + (size_t)N * DH;             // 896*128 bf16
  unsigned short* w_inT  = wT;                            // 128 x 256
  unsigned short* w_gcnT = w_inT + 128 * 256;             // 3 x 128 x 128
  unsigned short* w_nc1T = w_gcnT + 3 * 128 * 128;
  unsigned short* w_oc1T = w_nc1T + 128 * 128;
  float* dinv = (float*)(w_oc1T + 128 * 128);            // N
  int* cnt    = (int*)(dinv + N);                        // N
  int* rowptr = cnt + N;                                 // N+1
  int* cursor = rowptr + N + 1;                          // N
  int* bsum   = cursor + N;                              // 64
  int* csr    = bsum + 64;                               // E

  hipMemsetAsync(cnt, 0, N * sizeof(int), stream);
  hipMemsetAsync(cursor, 0, N * sizeof(int), stream);
  hipMemsetAsync(out_err, 0, 4 * (size_t)N * sizeof(float), stream);

  // weight transposes + conversions
  wtrans_kernel<<<(256 * DH + 255) / 256, 256, 0, stream>>>(w_in, w_inT, 256);
  for (int l = 0; l < 3; l++)
    wtrans_kernel<<<(DH * DH + 255) / 256, 256, 0, stream>>>(
        w_gcn + (size_t)l * DH * DH, w_gcnT + (size_t)l * DH * DH, DH);
  wtrans_kernel<<<(DH * DH + 255) / 256, 256, 0, stream>>>(w_nc1, w_nc1T, DH);
  wtrans_kernel<<<(DH * DH + 255) / 256, 256, 0, stream>>>(w_oc1, w_oc1T, DH);

  // CSR build
  const int eb = (E + 255) / 256;
  count_kernel<<<eb, 256, 0, stream>>>(ecol, cnt, E);
  const int nb1 = (N + 1023) / 1024;
  scan1_kernel<<<nb1, 1024, 0, stream>>>(cnt, rowptr, dinv, bsum, N);
  scan2_kernel<<<1, 64, 0, stream>>>(bsum, nb1, rowptr + N);
  scan3_kernel<<<(N + 255) / 256, 256, 0, stream>>>(rowptr, bsum, N);
  fill_kernel<<<eb, 256, 0, stream>>>(erow, ecol, rowptr, cursor, csr, E);

  const int mb = (N + 127) / 128;
  // h = relu(x @ w_in + b_in), also hb = bf16(h)
  gemm_kernel<256, true, 1><<<mb, 256, 0, stream>>>(x, w_inT, b_in, h, hb, N);
  // 3 GCN layers
  for (int l = 0; l < 3; l++) {
    gemm_kernel<128, false, 0><<<mb, 256, 0, stream>>>(hb, w_gcnT + (size_t)l * DH * DH,
                                                       nullptr, nullptr, xwb, N);
    agg_kernel<<<(N + 3) / 4, 256, 0, stream>>>((const unsigned int*)xwb, dinv, rowptr, csr,
                                                b_gcn + (size_t)l * DH, h,
                                                (unsigned int*)hb, N);
  }
  // heads (reuse xwb as hidden buffer)
  gemm_kernel<128, false, 2><<<mb, 256, 0, stream>>>(hb, w_nc1T, b_nc1, nullptr, xwb, N);
  mlp_out_kernel<<<(N + 3) / 4, 256, 0, stream>>>((const unsigned int*)xwb, w_nc2, b_nc2,
                                                  out_node, N);
  gemm_kernel<128, false, 2><<<mb, 256, 0, stream>>>(hb, w_oc1T, b_oc1, nullptr, xwb, N);
  mlp_out_kernel<<<(N + 3) / 4, 256, 0, stream>>>((const unsigned int*)xwb, w_oc2, b_oc2,
                                                  out_orig, N);
}

// Round 3
// 286.492 us; speedup vs baseline: 1.9562x; 1.1281x over previous
//
#include <hip/hip_runtime.h>
#include <math.h>

#define DH 128

typedef short short8 __attribute__((ext_vector_type(8)));
typedef float f32x4 __attribute__((ext_vector_type(4)));

__device__ __forceinline__ unsigned short f2bu(float f) {
  unsigned int u = __builtin_bit_cast(unsigned int, f);
  unsigned int r = (u + 0x7fffu + ((u >> 16) & 1u)) >> 16;
  return (unsigned short)r;
}
__device__ __forceinline__ float blo(unsigned int u) {
  return __builtin_bit_cast(float, u << 16);
}
__device__ __forceinline__ float bhi(unsigned int u) {
  return __builtin_bit_cast(float, u & 0xffff0000u);
}
__device__ __forceinline__ unsigned int packb2(float a, float b) {
  return (unsigned int)f2bu(a) | ((unsigned int)f2bu(b) << 16);
}

// ---------------- all weight transposes fp32 [K][128] -> bf16 [128][K] ----------------
// segments: w_in (256x128), w_gcn (3 x 128x128), w_nc1, w_oc1

__global__ __launch_bounds__(256) void wtrans_all_kernel(
    const float* __restrict__ w_in, const float* __restrict__ w_gcn,
    const float* __restrict__ w_nc1, const float* __restrict__ w_oc1,
    unsigned short* __restrict__ w_inT, unsigned short* __restrict__ w_gcnT,
    unsigned short* __restrict__ w_nc1T, unsigned short* __restrict__ w_oc1T) {
  int idx = blockIdx.x * 256 + threadIdx.x;
  if (idx < 32768) {  // w_in: K=256
    int k = idx >> 7, c = idx & 127;
    w_inT[c * 256 + k] = f2bu(w_in[idx]);
  } else if (idx < 32768 + 49152) {  // 3 gcn layers
    int sub = idx - 32768;
    int off = sub & 16383;
    int k = off >> 7, c = off & 127;
    w_gcnT[(sub >> 14) * 16384 + c * 128 + k] = f2bu(w_gcn[sub]);
  } else if (idx < 32768 + 49152 + 16384) {
    int off = idx - 81920;
    int k = off >> 7, c = off & 127;
    w_nc1T[c * 128 + k] = f2bu(w_nc1[off]);
  } else if (idx < 114688) {
    int off = idx - 98304;
    int k = off >> 7, c = off & 127;
    w_oc1T[c * 128 + k] = f2bu(w_oc1[off]);
  }
}

// ---------------- CSR build ----------------

__global__ void count_kernel(const int* __restrict__ col, int* __restrict__ cnt, int e) {
  int i = blockIdx.x * blockDim.x + threadIdx.x;
  if (i < e) atomicAdd(&cnt[col[i]], 1);
}

__global__ __launch_bounds__(1024) void scan1_kernel(const int* __restrict__ cnt,
                                                     int* __restrict__ rowptr,
                                                     float* __restrict__ dinv,
                                                     int* __restrict__ bsum, int n) {
  __shared__ int wsum[16];
  const int t = threadIdx.x;
  const int lane = t & 63, wid = t >> 6;
  const int i = blockIdx.x * 1024 + t;
  int v = (i < n) ? cnt[i] : 0;
  int s = v;
#pragma unroll
  for (int d = 1; d < 64; d <<= 1) {
    int u = __shfl_up(s, d);
    if (lane >= d) s += u;
  }
  if (lane == 63) wsum[wid] = s;
  __syncthreads();
  if (t < 16) {
    int ws = wsum[t];
#pragma unroll
    for (int d = 1; d < 16; d <<= 1) {
      int u = __shfl_up(ws, d);
      if (t >= d) ws += u;
    }
    wsum[t] = ws;
  }
  __syncthreads();
  if (i < n) {
    rowptr[i] = (wid ? wsum[wid - 1] : 0) + s - v;
    dinv[i] = rsqrtf((float)(v + 1));
  }
  if (t == 0) bsum[blockIdx.x] = wsum[15];
}

__global__ void scan2_kernel(int* __restrict__ bsum, int nb, int* __restrict__ rowptr_n) {
  int lane = threadIdx.x;
  int v = (lane < nb) ? bsum[lane] : 0;
  int s = v;
#pragma unroll
  for (int d = 1; d < 64; d <<= 1) {
    int u = __shfl_up(s, d);
    if (lane >= d) s += u;
  }
  if (lane < nb) bsum[lane] = s - v;
  if (lane == 63) *rowptr_n = s;
}

__global__ void scan3_kernel(int* __restrict__ rowptr, const int* __restrict__ bsum, int n) {
  int i = blockIdx.x * 256 + threadIdx.x;
  if (i < n) rowptr[i] += bsum[i >> 10];
}

__global__ void fill_kernel(const int* __restrict__ row, const int* __restrict__ col,
                            const int* __restrict__ rowptr, int* __restrict__ cursor,
                            int* __restrict__ csr_src, int e) {
  int i = blockIdx.x * blockDim.x + threadIdx.x;
  if (i < e) {
    int c = col[i];
    int pos = rowptr[c] + atomicAdd(&cursor[c], 1);
    csr_src[pos] = row[i];
  }
}

// ---------------- bf16 MFMA GEMM: C[n,128] = A[n,K] @ W[K,128] ----------------
// WT is bf16 [128][K]. MODE 0: store bf16 raw. MODE 1: bias+relu, store fp32 + bf16.

template <int K, bool A_FP32, int MODE>
__global__ __launch_bounds__(256) void gemm_kernel(const void* __restrict__ A_,
                                                   const unsigned short* __restrict__ WT,
                                                   const float* __restrict__ bias,
                                                   float* __restrict__ Cf,
                                                   unsigned short* __restrict__ Cb, int n) {
  const int t = threadIdx.x;
  const int lane = t & 63;
  const int w = t >> 6;
  const int wr = w >> 1, wc = w & 1;
  const int lr = lane & 15, lg = lane >> 4;
  const int r_base = blockIdx.x * 128 + wr * 64;
  const int c_base = wc * 64;

  f32x4 acc[4][4] = {};

#pragma unroll
  for (int kk = 0; kk < K / 32; kk++) {
    const int koff = kk * 32 + lg * 8;
    short8 a[4], b[4];
#pragma unroll
    for (int m = 0; m < 4; m++) {
      int row = r_base + m * 16 + lr;
      row = row < n ? row : n - 1;
      if (A_FP32) {
        const float* Af = (const float*)A_;
        float4 p = *(const float4*)&Af[(size_t)row * K + koff];
        float4 q = *(const float4*)&Af[(size_t)row * K + koff + 4];
        short8 av;
        av[0] = (short)f2bu(p.x); av[1] = (short)f2bu(p.y);
        av[2] = (short)f2bu(p.z); av[3] = (short)f2bu(p.w);
        av[4] = (short)f2bu(q.x); av[5] = (short)f2bu(q.y);
        av[6] = (short)f2bu(q.z); av[7] = (short)f2bu(q.w);
        a[m] = av;
      } else {
        const unsigned short* Ab = (const unsigned short*)A_;
        a[m] = *(const short8*)&Ab[(size_t)row * K + koff];
      }
    }
#pragma unroll
    for (int nb = 0; nb < 4; nb++) {
      int col = c_base + nb * 16 + lr;
      b[nb] = *(const short8*)&WT[(size_t)col * K + koff];
    }
#pragma unroll
    for (int m = 0; m < 4; m++)
#pragma unroll
      for (int nb = 0; nb < 4; nb++)
        acc[m][nb] = __builtin_amdgcn_mfma_f32_16x16x32_bf16(a[m], b[nb], acc[m][nb], 0, 0, 0);
  }

  float bcol[4];
  if (MODE != 0) {
#pragma unroll
    for (int nb = 0; nb < 4; nb++) bcol[nb] = bias[c_base + nb * 16 + lr];
  }

#pragma unroll
  for (int m = 0; m < 4; m++) {
#pragma unroll
    for (int i = 0; i < 4; i++) {
      int row = r_base + m * 16 + lg * 4 + i;
      if (row < n) {
#pragma unroll
        for (int nb = 0; nb < 4; nb++) {
          int col = c_base + nb * 16 + lr;
          float v = acc[m][nb][i];
          if (MODE != 0) {
            v = fmaxf(v + bcol[nb], 0.f);
            Cf[(size_t)row * DH + col] = v;
          }
          Cb[(size_t)row * DH + col] = f2bu(v);
        }
      }
    }
  }
}

// ---------------- aggregation: h = relu(h + D^-1/2 (A+I) D^-1/2 (h W) + b) ----------------
// One wave per node; half-waves process alternate edges; uint2 (4 bf16) per lane.

__global__ __launch_bounds__(256) void agg_kernel(const uint2* __restrict__ xwb2,
                                                  const float* __restrict__ dinv,
                                                  const int* __restrict__ rowptr,
                                                  const int* __restrict__ csr,
                                                  const float* __restrict__ bias,
                                                  float* __restrict__ h,
                                                  uint2* __restrict__ hb2, int n) {
  const int node = blockIdx.x * 4 + (threadIdx.x >> 6);
  if (node >= n) return;
  const int lane = threadIdx.x & 63;
  const int half = lane >> 5;
  const int cidx = lane & 31;
  const float self = dinv[node];

  uint2 su = xwb2[(size_t)node * 32 + cidx];
  const float sw = half ? 0.f : self * self;  // self loop counted once
  float a0 = sw * blo(su.x), a1 = sw * bhi(su.x);
  float a2 = sw * blo(su.y), a3 = sw * bhi(su.y);

  const int beg = rowptr[node], end = rowptr[node + 1];
  int j = beg;
  for (; j + 8 <= end; j += 8) {
    int s0 = csr[j + half], s1 = csr[j + 2 + half];
    int s2 = csr[j + 4 + half], s3 = csr[j + 6 + half];
    float w0 = dinv[s0] * self, w1 = dinv[s1] * self;
    float w2 = dinv[s2] * self, w3 = dinv[s3] * self;
    uint2 u0 = xwb2[(size_t)s0 * 32 + cidx];
    uint2 u1 = xwb2[(size_t)s1 * 32 + cidx];
    uint2 u2 = xwb2[(size_t)s2 * 32 + cidx];
    uint2 u3 = xwb2[(size_t)s3 * 32 + cidx];
    a0 = fmaf(w0, blo(u0.x), a0); a1 = fmaf(w0, bhi(u0.x), a1);
    a2 = fmaf(w0, blo(u0.y), a2); a3 = fmaf(w0, bhi(u0.y), a3);
    a0 = fmaf(w1, blo(u1.x), a0); a1 = fmaf(w1, bhi(u1.x), a1);
    a2 = fmaf(w1, blo(u1.y), a2); a3 = fmaf(w1, bhi(u1.y), a3);
    a0 = fmaf(w2, blo(u2.x), a0); a1 = fmaf(w2, bhi(u2.x), a1);
    a2 = fmaf(w2, blo(u2.y), a2); a3 = fmaf(w2, bhi(u2.y), a3);
    a0 = fmaf(w3, blo(u3.x), a0); a1 = fmaf(w3, bhi(u3.x), a1);
    a2 = fmaf(w3, blo(u3.y), a2); a3 = fmaf(w3, bhi(u3.y), a3);
  }
  for (; j < end; j += 2) {
    int jj = j + half;
    int s = csr[jj < end ? jj : j];
    float w = jj < end ? dinv[s] * self : 0.f;
    uint2 u = xwb2[(size_t)s * 32 + cidx];
    a0 = fmaf(w, blo(u.x), a0); a1 = fmaf(w, bhi(u.x), a1);
    a2 = fmaf(w, blo(u.y), a2); a3 = fmaf(w, bhi(u.y), a3);
  }

  a0 += __shfl_xor(a0, 32);
  a1 += __shfl_xor(a1, 32);
  a2 += __shfl_xor(a2, 32);
  a3 += __shfl_xor(a3, 32);

  if (half == 0) {
    const float4 bv = *(const float4*)&bias[cidx * 4];
    const float4 hv = *(const float4*)&h[(size_t)node * DH + cidx * 4];
    float r0 = fmaxf(hv.x + a0 + bv.x, 0.f);
    float r1 = fmaxf(hv.y + a1 + bv.y, 0.f);
    float r2 = fmaxf(hv.z + a2 + bv.z, 0.f);
    float r3 = fmaxf(hv.w + a3 + bv.w, 0.f);
    *(float4*)&h[(size_t)node * DH + cidx * 4] = make_float4(r0, r1, r2, r3);
    hb2[(size_t)node * 32 + cidx] = make_uint2(packb2(r0, r1), packb2(r2, r3));
  }
}

// ---------------- fused dual MLP head ----------------
// out = sigmoid(relu(hb @ W1 + b1) . w2 + b2) for both heads; hidden stays in regs.

__global__ __launch_bounds__(256) void heads_kernel(
    const unsigned short* __restrict__ hb,
    const unsigned short* __restrict__ w1T_a, const float* __restrict__ b1_a,
    const float* __restrict__ w2_a, const float* __restrict__ b2_a,
    const unsigned short* __restrict__ w1T_b, const float* __restrict__ b1_b,
    const float* __restrict__ w2_b, const float* __restrict__ b2_b,
    float* __restrict__ out_a, float* __restrict__ out_b, int n) {
  const int t = threadIdx.x;
  const int lane = t & 63;
  const int w = t >> 6;
  const int lr = lane & 15, lg = lane >> 4;
  const int r_base = blockIdx.x * 128 + w * 32;

#pragma unroll
  for (int head = 0; head < 2; head++) {
    const unsigned short* W1T = head ? w1T_b : w1T_a;
    const float* b1 = head ? b1_b : b1_a;
    const float* w2 = head ? w2_b : w2_a;
    const float b2 = head ? b2_b[0] : b2_a[0];
    float* out = head ? out_b : out_a;

    f32x4 acc[2][8] = {};
#pragma unroll
    for (int kk = 0; kk < 4; kk++) {
      const int koff = kk * 32 + lg * 8;
      short8 a[2];
#pragma unroll
      for (int m = 0; m < 2; m++) {
        int row = r_base + m * 16 + lr;
        row = row < n ? row : n - 1;
        a[m] = *(const short8*)&hb[(size_t)row * DH + koff];
      }
#pragma unroll
      for (int nb = 0; nb < 8; nb++) {
        short8 b = *(const short8*)&W1T[(size_t)(nb * 16 + lr) * DH + koff];
#pragma unroll
        for (int m = 0; m < 2; m++)
          acc[m][nb] = __builtin_amdgcn_mfma_f32_16x16x32_bf16(a[m], b, acc[m][nb], 0, 0, 0);
      }
    }

    float b1v[8], w2v[8];
#pragma unroll
    for (int nb = 0; nb < 8; nb++) {
      b1v[nb] = b1[nb * 16 + lr];
      w2v[nb] = w2[nb * 16 + lr];
    }

#pragma unroll
    for (int m = 0; m < 2; m++) {
#pragma unroll
      for (int i = 0; i < 4; i++) {
        float s = 0.f;
#pragma unroll
        for (int nb = 0; nb < 8; nb++)
          s += fmaxf(acc[m][nb][i] + b1v[nb], 0.f) * w2v[nb];
        s += __shfl_xor(s, 1);
        s += __shfl_xor(s, 2);
        s += __shfl_xor(s, 4);
        s += __shfl_xor(s, 8);
        int row = r_base + m * 16 + lg * 4 + i;
        if (lr == 0 && row < n) out[row] = 1.f / (1.f + __expf(-(s + b2)));
      }
    }
  }
}

// ---------------- launch ----------------

extern "C" void kernel_launch(void* const* d_in, const int* in_sizes, int n_in,
                              void* d_out, int out_size, void* d_ws, size_t ws_size,
                              hipStream_t stream) {
  const float* x     = (const float*)d_in[0];
  const int*   ei    = (const int*)d_in[1];
  const float* w_in  = (const float*)d_in[2];
  const float* b_in  = (const float*)d_in[3];
  const float* w_gcn = (const float*)d_in[4];
  const float* b_gcn = (const float*)d_in[5];
  const float* w_nc1 = (const float*)d_in[6];
  const float* b_nc1 = (const float*)d_in[7];
  const float* w_nc2 = (const float*)d_in[8];
  const float* b_nc2 = (const float*)d_in[9];
  const float* w_oc1 = (const float*)d_in[10];
  const float* b_oc1 = (const float*)d_in[11];
  const float* w_oc2 = (const float*)d_in[12];
  const float* b_oc2 = (const float*)d_in[13];

  const int N = in_sizes[0] / 256;  // 50000
  const int E = in_sizes[1] / 2;    // 600000
  const int* erow = ei;
  const int* ecol = ei + E;

  float* out      = (float*)d_out;
  float* out_node = out;
  float* out_orig = out + N;
  float* out_err  = out + 2 * (size_t)N;
  float* h        = out + 6 * (size_t)N;  // final h lives directly in d_out

  // workspace carve
  unsigned short* xwb = (unsigned short*)d_ws;            // N*128 bf16
  unsigned short* hb  = xwb + (size_t)N * DH;             // N*128 bf16
  unsigned short* w_inT  = hb + (size_t)N * DH;           // 128 x 256
  unsigned short* w_gcnT = w_inT + 128 * 256;             // 3 x 128 x 128
  unsigned short* w_nc1T = w_gcnT + 3 * 128 * 128;
  unsigned short* w_oc1T = w_nc1T + 128 * 128;
  float* dinv = (float*)(w_oc1T + 128 * 128);             // N
  int* cnt    = (int*)(dinv + N);                         // N
  int* cursor = cnt + N;                                  // N (adjacent to cnt)
  int* rowptr = cursor + N;                               // N+1
  int* bsum   = rowptr + N + 1;                           // 64
  int* csr    = bsum + 64;                                // E

  hipMemsetAsync(cnt, 0, 2 * (size_t)N * sizeof(int), stream);  // cnt + cursor
  hipMemsetAsync(out_err, 0, 4 * (size_t)N * sizeof(float), stream);

  wtrans_all_kernel<<<448, 256, 0, stream>>>(w_in, w_gcn, w_nc1, w_oc1,
                                             w_inT, w_gcnT, w_nc1T, w_oc1T);

  // CSR build
  const int eb = (E + 255) / 256;
  count_kernel<<<eb, 256, 0, stream>>>(ecol, cnt, E);
  const int nb1 = (N + 1023) / 1024;
  scan1_kernel<<<nb1, 1024, 0, stream>>>(cnt, rowptr, dinv, bsum, N);
  scan2_kernel<<<1, 64, 0, stream>>>(bsum, nb1, rowptr + N);
  scan3_kernel<<<(N + 255) / 256, 256, 0, stream>>>(rowptr, bsum, N);
  fill_kernel<<<eb, 256, 0, stream>>>(erow, ecol, rowptr, cursor, csr, E);

  const int mb = (N + 127) / 128;
  // h = relu(x @ w_in + b_in), also hb = bf16(h)
  gemm_kernel<256, true, 1><<<mb, 256, 0, stream>>>(x, w_inT, b_in, h, hb, N);
  // 3 GCN layers
  for (int l = 0; l < 3; l++) {
    gemm_kernel<128, false, 0><<<mb, 256, 0, stream>>>(hb, w_gcnT + (size_t)l * DH * DH,
                                                       nullptr, nullptr, xwb, N);
    agg_kernel<<<(N + 3) / 4, 256, 0, stream>>>((const uint2*)xwb, dinv, rowptr, csr,
                                                b_gcn + (size_t)l * DH, h,
                                                (uint2*)hb, N);
  }
  // fused heads
  heads_kernel<<<mb, 256, 0, stream>>>(hb, w_nc1T, b_nc1, w_nc2, b_nc2,
                                       w_oc1T, b_oc1, w_oc2, b_oc2,
                                       out_node, out_orig, N);
}

// Round 4
// 258.449 us; speedup vs baseline: 2.1684x; 1.1085x over previous
//
#include <hip/hip_runtime.h>
#include <math.h>

#define DH 128

typedef short short8 __attribute__((ext_vector_type(8)));
typedef float f32x4 __attribute__((ext_vector_type(4)));

__device__ __forceinline__ unsigned short f2bu(float f) {
  unsigned int u = __builtin_bit_cast(unsigned int, f);
  unsigned int r = (u + 0x7fffu + ((u >> 16) & 1u)) >> 16;
  return (unsigned short)r;
}
__device__ __forceinline__ float blo(unsigned int u) {
  return __builtin_bit_cast(float, u << 16);
}
__device__ __forceinline__ float bhi(unsigned int u) {
  return __builtin_bit_cast(float, u & 0xffff0000u);
}
__device__ __forceinline__ unsigned int packb2(float a, float b) {
  return (unsigned int)f2bu(a) | ((unsigned int)f2bu(b) << 16);
}

// ---------------- prep: weight transposes (fp32 [K][128] -> bf16 [128][K]) + zeroing ----------------
// ranges: w_in 32768 | w_gcn 49152 | w_nc1 16384 | w_oc1 16384 | cnt 50000 | out_err 200000

__global__ __launch_bounds__(256) void prep_kernel(
    const float* __restrict__ w_in, const float* __restrict__ w_gcn,
    const float* __restrict__ w_nc1, const float* __restrict__ w_oc1,
    unsigned short* __restrict__ w_inT, unsigned short* __restrict__ w_gcnT,
    unsigned short* __restrict__ w_nc1T, unsigned short* __restrict__ w_oc1T,
    int* __restrict__ cnt, float* __restrict__ out_err, int n) {
  int idx = blockIdx.x * 256 + threadIdx.x;
  if (idx < 32768) {  // w_in: K=256
    int k = idx >> 7, c = idx & 127;
    w_inT[c * 256 + k] = f2bu(w_in[idx]);
  } else if (idx < 81920) {  // 3 gcn layers
    int sub = idx - 32768;
    int off = sub & 16383;
    int k = off >> 7, c = off & 127;
    w_gcnT[(sub >> 14) * 16384 + c * 128 + k] = f2bu(w_gcn[sub]);
  } else if (idx < 98304) {
    int off = idx - 81920;
    int k = off >> 7, c = off & 127;
    w_nc1T[c * 128 + k] = f2bu(w_nc1[off]);
  } else if (idx < 114688) {
    int off = idx - 98304;
    int k = off >> 7, c = off & 127;
    w_oc1T[c * 128 + k] = f2bu(w_oc1[off]);
  } else if (idx < 114688 + n) {
    cnt[idx - 114688] = 0;
  } else if (idx < 114688 + 5 * n) {
    out_err[idx - 114688 - n] = 0.f;
  }
}

// ---------------- CSR build ----------------
// count also records each edge's within-node rank (atomic return value).

__global__ void count_kernel(const int* __restrict__ col, int* __restrict__ cnt,
                             int* __restrict__ rank, int e) {
  int i = blockIdx.x * blockDim.x + threadIdx.x;
  if (i < e) rank[i] = atomicAdd(&cnt[col[i]], 1);
}

__global__ __launch_bounds__(1024) void scan1_kernel(const int* __restrict__ cnt,
                                                     int* __restrict__ rowptr,
                                                     float* __restrict__ dinv,
                                                     int* __restrict__ bsum, int n) {
  __shared__ int wsum[16];
  const int t = threadIdx.x;
  const int lane = t & 63, wid = t >> 6;
  const int i = blockIdx.x * 1024 + t;
  int v = (i < n) ? cnt[i] : 0;
  int s = v;
#pragma unroll
  for (int d = 1; d < 64; d <<= 1) {
    int u = __shfl_up(s, d);
    if (lane >= d) s += u;
  }
  if (lane == 63) wsum[wid] = s;
  __syncthreads();
  if (t < 16) {
    int ws = wsum[t];
#pragma unroll
    for (int d = 1; d < 16; d <<= 1) {
      int u = __shfl_up(ws, d);
      if (t >= d) ws += u;
    }
    wsum[t] = ws;
  }
  __syncthreads();
  if (i < n) {
    rowptr[i] = (wid ? wsum[wid - 1] : 0) + s - v;
    dinv[i] = rsqrtf((float)(v + 1));
  }
  if (t == 0) bsum[blockIdx.x] = wsum[15];
}

// adds block-prefix of bsum (computed in-wave per block) and writes rowptr[n]
__global__ __launch_bounds__(256) void scan3_kernel(int* __restrict__ rowptr,
                                                    const int* __restrict__ bsum,
                                                    int n, int nb) {
  __shared__ int pre[64];
  int total = 0;
  if (threadIdx.x < 64) {
    int v = (threadIdx.x < nb) ? bsum[threadIdx.x] : 0;
    int s = v;
#pragma unroll
    for (int d = 1; d < 64; d <<= 1) {
      int u = __shfl_up(s, d);
      if ((threadIdx.x & 63) >= d) s += u;
    }
    pre[threadIdx.x] = s - v;  // exclusive
    total = s;
  }
  __syncthreads();
  int i = blockIdx.x * 256 + threadIdx.x;
  if (i < n) rowptr[i] += pre[i >> 10];
  if (blockIdx.x == 0 && threadIdx.x == 63) rowptr[n] = total;
}

__global__ void fill_kernel(const int* __restrict__ row, const int* __restrict__ col,
                            const int* __restrict__ rowptr, const int* __restrict__ rank,
                            int* __restrict__ csr, int e) {
  int i = blockIdx.x * blockDim.x + threadIdx.x;
  if (i < e) csr[rowptr[col[i]] + rank[i]] = row[i];
}

// ---------------- bf16 MFMA GEMM: C[n,128] = A[n,K] @ W[K,128] ----------------
// WT is bf16 [128][K]. MODE 0: store bf16 scaled by dscale[row].
// MODE 1: bias+relu, store fp32 + bf16.

template <int K, bool A_FP32, int MODE>
__global__ __launch_bounds__(256) void gemm_kernel(const void* __restrict__ A_,
                                                   const unsigned short* __restrict__ WT,
                                                   const float* __restrict__ bias,
                                                   const float* __restrict__ dscale,
                                                   float* __restrict__ Cf,
                                                   unsigned short* __restrict__ Cb, int n) {
  const int t = threadIdx.x;
  const int lane = t & 63;
  const int w = t >> 6;
  const int wr = w >> 1, wc = w & 1;
  const int lr = lane & 15, lg = lane >> 4;
  const int r_base = blockIdx.x * 128 + wr * 64;
  const int c_base = wc * 64;

  f32x4 acc[4][4] = {};

#pragma unroll
  for (int kk = 0; kk < K / 32; kk++) {
    const int koff = kk * 32 + lg * 8;
    short8 a[4], b[4];
#pragma unroll
    for (int m = 0; m < 4; m++) {
      int row = r_base + m * 16 + lr;
      row = row < n ? row : n - 1;
      if (A_FP32) {
        const float* Af = (const float*)A_;
        float4 p = *(const float4*)&Af[(size_t)row * K + koff];
        float4 q = *(const float4*)&Af[(size_t)row * K + koff + 4];
        short8 av;
        av[0] = (short)f2bu(p.x); av[1] = (short)f2bu(p.y);
        av[2] = (short)f2bu(p.z); av[3] = (short)f2bu(p.w);
        av[4] = (short)f2bu(q.x); av[5] = (short)f2bu(q.y);
        av[6] = (short)f2bu(q.z); av[7] = (short)f2bu(q.w);
        a[m] = av;
      } else {
        const unsigned short* Ab = (const unsigned short*)A_;
        a[m] = *(const short8*)&Ab[(size_t)row * K + koff];
      }
    }
#pragma unroll
    for (int nb = 0; nb < 4; nb++) {
      int col = c_base + nb * 16 + lr;
      b[nb] = *(const short8*)&WT[(size_t)col * K + koff];
    }
#pragma unroll
    for (int m = 0; m < 4; m++)
#pragma unroll
      for (int nb = 0; nb < 4; nb++)
        acc[m][nb] = __builtin_amdgcn_mfma_f32_16x16x32_bf16(a[m], b[nb], acc[m][nb], 0, 0, 0);
  }

  float bcol[4];
  if (MODE != 0) {
#pragma unroll
    for (int nb = 0; nb < 4; nb++) bcol[nb] = bias[c_base + nb * 16 + lr];
  }

#pragma unroll
  for (int m = 0; m < 4; m++) {
#pragma unroll
    for (int i = 0; i < 4; i++) {
      int row = r_base + m * 16 + lg * 4 + i;
      if (row < n) {
        float sc = (MODE == 0) ? dscale[row] : 0.f;
#pragma unroll
        for (int nb = 0; nb < 4; nb++) {
          int col = c_base + nb * 16 + lr;
          float v = acc[m][nb][i];
          if (MODE == 0) {
            Cb[(size_t)row * DH + col] = f2bu(v * sc);
          } else {
            v = fmaxf(v + bcol[nb], 0.f);
            Cf[(size_t)row * DH + col] = v;
            Cb[(size_t)row * DH + col] = f2bu(v);
          }
        }
      }
    }
  }
}

// ---------------- aggregation: h = relu(h + self * sum(xwb') + b) ----------------
// xwb' rows are pre-scaled by dinv[src]; pure gather-add, final scale by dinv[node].

__global__ __launch_bounds__(256) void agg_kernel(const uint2* __restrict__ xwb2,
                                                  const float* __restrict__ dinv,
                                                  const int* __restrict__ rowptr,
                                                  const int* __restrict__ csr,
                                                  const float* __restrict__ bias,
                                                  float* __restrict__ h,
                                                  uint2* __restrict__ hb2, int n) {
  const int node = blockIdx.x * 4 + (threadIdx.x >> 6);
  if (node >= n) return;
  const int lane = threadIdx.x & 63;
  const int half = lane >> 5;
  const int cidx = lane & 31;
  const float self = dinv[node];

  float a0, a1, a2, a3;
  if (half == 0) {  // self loop counted once
    uint2 su = xwb2[(size_t)node * 32 + cidx];
    a0 = blo(su.x); a1 = bhi(su.x);
    a2 = blo(su.y); a3 = bhi(su.y);
  } else {
    a0 = a1 = a2 = a3 = 0.f;
  }

  const int beg = rowptr[node], end = rowptr[node + 1];
  int j = beg;
  for (; j + 8 <= end; j += 8) {
    int s0 = csr[j + half], s1 = csr[j + 2 + half];
    int s2 = csr[j + 4 + half], s3 = csr[j + 6 + half];
    uint2 u0 = xwb2[(size_t)s0 * 32 + cidx];
    uint2 u1 = xwb2[(size_t)s1 * 32 + cidx];
    uint2 u2 = xwb2[(size_t)s2 * 32 + cidx];
    uint2 u3 = xwb2[(size_t)s3 * 32 + cidx];
    a0 += blo(u0.x); a1 += bhi(u0.x); a2 += blo(u0.y); a3 += bhi(u0.y);
    a0 += blo(u1.x); a1 += bhi(u1.x); a2 += blo(u1.y); a3 += bhi(u1.y);
    a0 += blo(u2.x); a1 += bhi(u2.x); a2 += blo(u2.y); a3 += bhi(u2.y);
    a0 += blo(u3.x); a1 += bhi(u3.x); a2 += blo(u3.y); a3 += bhi(u3.y);
  }
  for (; j < end; j += 2) {
    int jj = j + half;
    if (jj < end) {
      int s = csr[jj];
      uint2 u = xwb2[(size_t)s * 32 + cidx];
      a0 += blo(u.x); a1 += bhi(u.x); a2 += blo(u.y); a3 += bhi(u.y);
    }
  }

  a0 += __shfl_xor(a0, 32);
  a1 += __shfl_xor(a1, 32);
  a2 += __shfl_xor(a2, 32);
  a3 += __shfl_xor(a3, 32);

  if (half == 0) {
    const float4 bv = *(const float4*)&bias[cidx * 4];
    const float4 hv = *(const float4*)&h[(size_t)node * DH + cidx * 4];
    float r0 = fmaxf(hv.x + self * a0 + bv.x, 0.f);
    float r1 = fmaxf(hv.y + self * a1 + bv.y, 0.f);
    float r2 = fmaxf(hv.z + self * a2 + bv.z, 0.f);
    float r3 = fmaxf(hv.w + self * a3 + bv.w, 0.f);
    *(float4*)&h[(size_t)node * DH + cidx * 4] = make_float4(r0, r1, r2, r3);
    hb2[(size_t)node * 32 + cidx] = make_uint2(packb2(r0, r1), packb2(r2, r3));
  }
}

// ---------------- fused dual MLP head ----------------

__global__ __launch_bounds__(256) void heads_kernel(
    const unsigned short* __restrict__ hb,
    const unsigned short* __restrict__ w1T_a, const float* __restrict__ b1_a,
    const float* __restrict__ w2_a, const float* __restrict__ b2_a,
    const unsigned short* __restrict__ w1T_b, const float* __restrict__ b1_b,
    const float* __restrict__ w2_b, const float* __restrict__ b2_b,
    float* __restrict__ out_a, float* __restrict__ out_b, int n) {
  const int t = threadIdx.x;
  const int lane = t & 63;
  const int w = t >> 6;
  const int lr = lane & 15, lg = lane >> 4;
  const int r_base = blockIdx.x * 128 + w * 32;

#pragma unroll
  for (int head = 0; head < 2; head++) {
    const unsigned short* W1T = head ? w1T_b : w1T_a;
    const float* b1 = head ? b1_b : b1_a;
    const float* w2 = head ? w2_b : w2_a;
    const float b2 = head ? b2_b[0] : b2_a[0];
    float* out = head ? out_b : out_a;

    f32x4 acc[2][8] = {};
#pragma unroll
    for (int kk = 0; kk < 4; kk++) {
      const int koff = kk * 32 + lg * 8;
      short8 a[2];
#pragma unroll
      for (int m = 0; m < 2; m++) {
        int row = r_base + m * 16 + lr;
        row = row < n ? row : n - 1;
        a[m] = *(const short8*)&hb[(size_t)row * DH + koff];
      }
#pragma unroll
      for (int nb = 0; nb < 8; nb++) {
        short8 b = *(const short8*)&W1T[(size_t)(nb * 16 + lr) * DH + koff];
#pragma unroll
        for (int m = 0; m < 2; m++)
          acc[m][nb] = __builtin_amdgcn_mfma_f32_16x16x32_bf16(a[m], b, acc[m][nb], 0, 0, 0);
      }
    }

    float b1v[8], w2v[8];
#pragma unroll
    for (int nb = 0; nb < 8; nb++) {
      b1v[nb] = b1[nb * 16 + lr];
      w2v[nb] = w2[nb * 16 + lr];
    }

#pragma unroll
    for (int m = 0; m < 2; m++) {
#pragma unroll
      for (int i = 0; i < 4; i++) {
        float s = 0.f;
#pragma unroll
        for (int nb = 0; nb < 8; nb++)
          s += fmaxf(acc[m][nb][i] + b1v[nb], 0.f) * w2v[nb];
        s += __shfl_xor(s, 1);
        s += __shfl_xor(s, 2);
        s += __shfl_xor(s, 4);
        s += __shfl_xor(s, 8);
        int row = r_base + m * 16 + lg * 4 + i;
        if (lr == 0 && row < n) out[row] = 1.f / (1.f + __expf(-(s + b2)));
      }
    }
  }
}

// ---------------- launch ----------------

extern "C" void kernel_launch(void* const* d_in, const int* in_sizes, int n_in,
                              void* d_out, int out_size, void* d_ws, size_t ws_size,
                              hipStream_t stream) {
  const float* x     = (const float*)d_in[0];
  const int*   ei    = (const int*)d_in[1];
  const float* w_in  = (const float*)d_in[2];
  const float* b_in  = (const float*)d_in[3];
  const float* w_gcn = (const float*)d_in[4];
  const float* b_gcn = (const float*)d_in[5];
  const float* w_nc1 = (const float*)d_in[6];
  const float* b_nc1 = (const float*)d_in[7];
  const float* w_nc2 = (const float*)d_in[8];
  const float* b_nc2 = (const float*)d_in[9];
  const float* w_oc1 = (const float*)d_in[10];
  const float* b_oc1 = (const float*)d_in[11];
  const float* w_oc2 = (const float*)d_in[12];
  const float* b_oc2 = (const float*)d_in[13];

  const int N = in_sizes[0] / 256;  // 50000
  const int E = in_sizes[1] / 2;    // 600000
  const int* erow = ei;
  const int* ecol = ei + E;

  float* out      = (float*)d_out;
  float* out_node = out;
  float* out_orig = out + N;
  float* out_err  = out + 2 * (size_t)N;
  float* h        = out + 6 * (size_t)N;  // final h lives directly in d_out

  // workspace carve
  unsigned short* xwb = (unsigned short*)d_ws;            // N*128 bf16
  unsigned short* hb  = xwb + (size_t)N * DH;             // N*128 bf16
  unsigned short* w_inT  = hb + (size_t)N * DH;           // 128 x 256
  unsigned short* w_gcnT = w_inT + 128 * 256;             // 3 x 128 x 128
  unsigned short* w_nc1T = w_gcnT + 3 * 128 * 128;
  unsigned short* w_oc1T = w_nc1T + 128 * 128;
  float* dinv = (float*)(w_oc1T + 128 * 128);             // N
  int* cnt    = (int*)(dinv + N);                         // N
  int* rowptr = cnt + N;                                  // N+1
  int* bsum   = rowptr + N + 1;                           // 64
  int* rank   = bsum + 64;                                // E
  int* csr    = rank + E;                                 // E

  // prep: weight transposes + zero cnt + zero out_err (one dispatch)
  prep_kernel<<<(114688 + 5 * N + 255) / 256, 256, 0, stream>>>(
      w_in, w_gcn, w_nc1, w_oc1, w_inT, w_gcnT, w_nc1T, w_oc1T, cnt, out_err, N);

  // CSR build
  const int eb = (E + 255) / 256;
  count_kernel<<<eb, 256, 0, stream>>>(ecol, cnt, rank, E);
  const int nb1 = (N + 1023) / 1024;
  scan1_kernel<<<nb1, 1024, 0, stream>>>(cnt, rowptr, dinv, bsum, N);
  scan3_kernel<<<(N + 255) / 256, 256, 0, stream>>>(rowptr, bsum, N, nb1);
  fill_kernel<<<eb, 256, 0, stream>>>(erow, ecol, rowptr, rank, csr, E);

  const int mb = (N + 127) / 128;
  // h = relu(x @ w_in + b_in), also hb = bf16(h)
  gemm_kernel<256, true, 1><<<mb, 256, 0, stream>>>(x, w_inT, b_in, nullptr, h, hb, N);
  // 3 GCN layers: xwb = dinv * (hb @ W); h = relu(h + dinv*sum(xwb) + b)
  for (int l = 0; l < 3; l++) {
    gemm_kernel<128, false, 0><<<mb, 256, 0, stream>>>(hb, w_gcnT + (size_t)l * DH * DH,
                                                       nullptr, dinv, nullptr, xwb, N);
    agg_kernel<<<(N + 3) / 4, 256, 0, stream>>>((const uint2*)xwb, dinv, rowptr, csr,
                                                b_gcn + (size_t)l * DH, h,
                                                (uint2*)hb, N);
  }
  // fused heads
  heads_kernel<<<mb, 256, 0, stream>>>(hb, w_nc1T, b_nc1, w_nc2, b_nc2,
                                       w_oc1T, b_oc1, w_oc2, b_oc2,
                                       out_node, out_orig, N);
}